// Round 9
// baseline (1415.167 us; speedup 1.0000x reference)
//
#include <hip/hip_runtime.h>
#include <hip/hip_fp16.h>
#include <cmath>

#define NN 100000
#define EE 1600000
#define INC 500
#define HIDC 128
#define OUTC 64
#define NLAYER 8
#define NW32 3125           // NN / 32 exactly
#define NW16 6250           // NN / 16 exactly
#define FUSE_BLKS 7032      // 9*781 + 3 : bid%9==0 -> gemm (782), else fill (6250)

typedef float f32x4 __attribute__((ext_vector_type(4)));
typedef __bf16 bf16x8 __attribute__((ext_vector_type(8)));
typedef _Float16 f16x8 __attribute__((ext_vector_type(8)));
typedef short s16x4 __attribute__((ext_vector_type(4)));
typedef short s16x8 __attribute__((ext_vector_type(8)));

__device__ __forceinline__ unsigned short f2bf_rn(float f) {
  unsigned u = __float_as_uint(f);
  unsigned r = u + 0x7fffu + ((u >> 16) & 1u);
  return (unsigned short)(r >> 16);
}
__device__ __forceinline__ float bf2f(unsigned short h) {
  return __uint_as_float(((unsigned)h) << 16);
}

// frag layout addr for (row, k), K pitch Kp: [(row/16)][k/8][row%16][k%8]
__device__ __forceinline__ int fraddr(int row, int k, int Kp) {
  return (row >> 4) * (Kp * 16) + (k >> 3) * 128 + (row & 15) * 8 + (k & 7);
}

// ---------------- graph preprocessing ----------------

__global__ void k_count_deg(const int* __restrict__ dst, int* __restrict__ deg, int E) {
  int e = blockIdx.x * blockDim.x + threadIdx.x;
  if (e < E) atomicAdd(&deg[dst[e]], 1);
}

__global__ void k_scan_block_sums(const int* __restrict__ deg, int* __restrict__ bsum, int n) {
  __shared__ int sm[256];
  int i = blockIdx.x * 256 + threadIdx.x;
  int v = (i < n) ? deg[i] + 1 : 0;  // +1 for self-loop
  sm[threadIdx.x] = v;
  __syncthreads();
  for (int s = 128; s > 0; s >>= 1) {
    if (threadIdx.x < s) sm[threadIdx.x] += sm[threadIdx.x + s];
    __syncthreads();
  }
  if (threadIdx.x == 0) bsum[blockIdx.x] = sm[0];
}

__global__ void k_scan_partials(int* __restrict__ bsum, int nb) {
  __shared__ int sm[512];
  int t = threadIdx.x;
  sm[t] = (t < nb) ? bsum[t] : 0;
  __syncthreads();
  for (int s = 1; s < 512; s <<= 1) {
    int v = (t >= s) ? sm[t - s] : 0;
    __syncthreads();
    sm[t] += v;
    __syncthreads();
  }
  if (t < nb) bsum[t] = (t == 0) ? 0 : sm[t - 1];  // exclusive
}

__global__ void k_scan_final(const int* __restrict__ deg, const int* __restrict__ bsum,
                             int* __restrict__ row_ptr, int n) {
  __shared__ int sm[256];
  int i = blockIdx.x * 256 + threadIdx.x;
  int v = (i < n) ? deg[i] + 1 : 0;
  sm[threadIdx.x] = v;
  __syncthreads();
  for (int s = 1; s < 256; s <<= 1) {
    int u = (threadIdx.x >= s) ? sm[threadIdx.x - s] : 0;
    __syncthreads();
    sm[threadIdx.x] += u;
    __syncthreads();
  }
  if (i < n) row_ptr[i] = bsum[blockIdx.x] + sm[threadIdx.x] - v;  // exclusive
}

__global__ void k_init_rows(const int* __restrict__ deg, const int* __restrict__ row_ptr,
                            int* __restrict__ cursor, int* __restrict__ col,
                            float* __restrict__ dinv, int n) {
  int i = blockIdx.x * blockDim.x + threadIdx.x;
  if (i < n) {
    int rp = row_ptr[i];
    col[rp] = i;          // self-loop entry first (deterministic)
    cursor[i] = rp + 1;
    dinv[i] = rsqrtf((float)(deg[i] + 1));
  }
}

// ---- W_in -> FRAGMENT layout hi/lo bf16, Kp=512 ----

__global__ void k_prep_wfin(const float* __restrict__ W, unsigned short* __restrict__ fh,
                            unsigned short* __restrict__ fl) {
  int i = blockIdx.x * 256 + threadIdx.x;
  if (i >= HIDC * 512) return;
  int n = i / 512, k = i % 512;
  float v = (k < INC) ? W[(size_t)k * HIDC + n] : 0.f;
  unsigned short h = f2bf_rn(v);
  unsigned short l = f2bf_rn(v - bf2f(h));
  int a = fraddr(n, k, 512);
  fh[a] = h;
  fl[a] = l;
}

// ---- W -> fp16 fragment layout, optional identity fold: M = idc*I + ws*W ----

__global__ void k_prep_wf16(const float* __restrict__ W, __half* __restrict__ f,
                            int K, int N, float idc, float ws) {
  int i = blockIdx.x * 256 + threadIdx.x;
  if (i >= N * K) return;
  int n = i / K, k = i % K;
  float v = ws * W[(size_t)k * N + n] + ((k == n) ? idc : 0.f);
  f[fraddr(n, k, K)] = __float2half(v);
}

// ---------------- FUSED: CSR edge fill  ∥  input-projection GEMM ----------------

__global__ void __launch_bounds__(256) k_fill_gemm(
    const int* __restrict__ src, const int* __restrict__ dst,
    int* __restrict__ cursor, int* __restrict__ col,
    const float* __restrict__ A, const unsigned short* __restrict__ Bfh,
    const unsigned short* __restrict__ Bfl, const float* __restrict__ bias,
    __half* __restrict__ C16u, __half* __restrict__ C16s,
    const float* __restrict__ dinv) {
  __shared__ __align__(16) unsigned short Ah[128 * 40];
  __shared__ __align__(16) unsigned short Al[128 * 40];
  int bid = blockIdx.x;
  int tid = threadIdx.x;

  if (bid % 9 != 0) {
    // ---------------- fill branch ----------------
    int fidx = bid - (bid / 9 + 1);
    int e = fidx * 256 + tid;
    if (e < EE) {
      int pos = atomicAdd(&cursor[dst[e]], 1);
      col[pos] = src[e];
    }
    return;
  }

  // ---------------- gemm branch ----------------
  int blk = bid / 9;
  int wid = tid >> 6, lane = tid & 63;
  int wr = wid >> 1, wc = wid & 1;
  int lr = lane & 15, kg = lane >> 4;
  int row0 = blk * 128;

  f32x4 acc[4][4];
#pragma unroll
  for (int m = 0; m < 4; ++m)
#pragma unroll
    for (int n = 0; n < 4; ++n) acc[m][n] = {0.f, 0.f, 0.f, 0.f};

  float4 va[4];
  auto issue_loads = [&](int kt) {
#pragma unroll
    for (int p = 0; p < 4; ++p) {
      int idx = tid + p * 256;
      int r = idx >> 3, kq = idx & 7;
      int gr = row0 + r, gk = kt + kq * 4;
      va[p] = make_float4(0.f, 0.f, 0.f, 0.f);
      if (gr < NN && gk < INC) va[p] = *reinterpret_cast<const float4*>(&A[(size_t)gr * INC + gk]);
    }
  };

  issue_loads(0);
  for (int kt = 0; kt < 512; kt += 32) {
    // convert regs -> LDS (hi/lo bf16)
#pragma unroll
    for (int p = 0; p < 4; ++p) {
      int idx = tid + p * 256;
      int r = idx >> 3, kq = idx & 7;
      const float* vp = &va[p].x;
      s16x4 h4, l4;
#pragma unroll
      for (int e = 0; e < 4; ++e) {
        unsigned short h = f2bf_rn(vp[e]);
        h4[e] = (short)h;
        l4[e] = (short)f2bf_rn(vp[e] - bf2f(h));
      }
      *reinterpret_cast<s16x4*>(&Ah[r * 40 + kq * 4]) = h4;
      *reinterpret_cast<s16x4*>(&Al[r * 40 + kq * 4]) = l4;
    }
    __syncthreads();
    if (kt + 32 < 512) issue_loads(kt + 32);  // overlaps MFMA below

    bf16x8 afh[4], afl[4];
#pragma unroll
    for (int m = 0; m < 4; ++m) {
      int r = wr * 64 + m * 16 + lr;
      afh[m] = *reinterpret_cast<const bf16x8*>(&Ah[r * 40 + kg * 8]);
      afl[m] = *reinterpret_cast<const bf16x8*>(&Al[r * 40 + kg * 8]);
    }
#pragma unroll
    for (int n = 0; n < 4; ++n) {
      size_t bb = (size_t)(wc * 4 + n) * 8192 + (size_t)(kt / 8 + kg) * 128 + lr * 8;
      bf16x8 bh = *reinterpret_cast<const bf16x8*>(&Bfh[bb]);
      bf16x8 bl = *reinterpret_cast<const bf16x8*>(&Bfl[bb]);
#pragma unroll
      for (int m = 0; m < 4; ++m) {
        acc[m][n] = __builtin_amdgcn_mfma_f32_16x16x32_bf16(afh[m], bh, acc[m][n], 0, 0, 0);
        acc[m][n] = __builtin_amdgcn_mfma_f32_16x16x32_bf16(afl[m], bh, acc[m][n], 0, 0, 0);
        acc[m][n] = __builtin_amdgcn_mfma_f32_16x16x32_bf16(afh[m], bl, acc[m][n], 0, 0, 0);
      }
    }
    __syncthreads();
  }

  // epilogue: C(row = m*16 + kg*4 + q, col = n*16 + lr)
#pragma unroll
  for (int m = 0; m < 4; ++m) {
#pragma unroll
    for (int n = 0; n < 4; ++n) {
      int gc = wc * 64 + n * 16 + lr;
#pragma unroll
      for (int q = 0; q < 4; ++q) {
        int gr = row0 + wr * 64 + m * 16 + kg * 4 + q;
        if (gr < NN) {
          float v = fmaxf(acc[m][n][q] + bias[gc], 0.f);
          C16u[(size_t)gr * HIDC + gc] = __float2half(v);
          C16s[(size_t)gr * HIDC + gc] = __float2half(v * dinv[gr]);
        }
      }
    }
  }
}

// ---------------- FUSED layer: agg(16 nodes/wave -> LDS) + 16x128 GEMM ----------------
// z_r = 0.9*dinv_r*sum(hs_src) + 0.1*h0_r  (fp16, LDS, XOR-swizzled)
// then C = epi(z @ M)  with M = (1-b)I + bW pre-folded fp16 frag layout.
// EPI 0: relu -> fp16 scaled row-major (feeds next layer's agg)
// EPI 1: relu -> fp16 frag layout (last layer, feeds out GEMM)

template <int EPI>
__global__ void __launch_bounds__(256) k_layer(
    const __half* __restrict__ hs, const __half* __restrict__ h0u,
    const __half* __restrict__ Bf,
    const int* __restrict__ row_ptr, const int* __restrict__ deg,
    const int* __restrict__ col, const float* __restrict__ dinv,
    __half* __restrict__ Cs, __half* __restrict__ Cff) {
  __shared__ __half zbuf[4][16 * 128];   // 16 KB
  int wv = threadIdx.x >> 6, lane = threadIdx.x & 63;
  int w16 = blockIdx.x * 4 + wv;
  bool act = (w16 < NW16);
  int g = lane >> 4;    // edge slot within chunk
  int fl = lane & 15;   // feature sub-lane
  int row0 = w16 * 16;
  __half* zb = zbuf[wv];

  if (act) {
    for (int r = 0; r < 16; ++r) {
      int node = row0 + r;
      int start = row_ptr[node];
      int cnt = deg[node] + 1;
      int nch = (cnt + 3) >> 2;

      float acc[8];
#pragma unroll
      for (int j = 0; j < 8; ++j) acc[j] = 0.f;

      auto load_chunk = [&](int ch, s16x8& v, float& m) {
        int e = ch * 4 + g;
        bool valid = e < cnt;
        int c = col[start + (valid ? e : 0)];
        m = valid ? 1.f : 0.f;
        v = *reinterpret_cast<const s16x8*>(&hs[(size_t)c * HIDC + fl * 8]);
      };

      s16x8 curv; float curm;
      load_chunk(0, curv, curm);
      for (int ch = 0; ch < nch; ++ch) {
        s16x8 nv = {}; float nm = 0.f;
        if (ch + 1 < nch) load_chunk(ch + 1, nv, nm);
        const __half2* hp = reinterpret_cast<const __half2*>(&curv);
#pragma unroll
        for (int j = 0; j < 4; ++j) {
          float2 f = __half22float2(hp[j]);
          acc[2 * j]     = fmaf(curm, f.x, acc[2 * j]);
          acc[2 * j + 1] = fmaf(curm, f.y, acc[2 * j + 1]);
        }
        curv = nv; curm = nm;
      }

#pragma unroll
      for (int j = 0; j < 8; ++j) {
        acc[j] += __shfl_xor(acc[j], 16, 64);
        acc[j] += __shfl_xor(acc[j], 32, 64);
      }

      if (g == 0) {
        float dr = dinv[node] * 0.9f;
        s16x8 r0 = *reinterpret_cast<const s16x8*>(&h0u[(size_t)node * HIDC + fl * 8]);
        const __half2* r0p = reinterpret_cast<const __half2*>(&r0);
        f16x8 w;
#pragma unroll
        for (int j = 0; j < 4; ++j) {
          float2 f0 = __half22float2(r0p[j]);
          w[2 * j]     = (_Float16)fmaf(dr, acc[2 * j],     0.1f * f0.x);
          w[2 * j + 1] = (_Float16)fmaf(dr, acc[2 * j + 1], 0.1f * f0.y);
        }
        *reinterpret_cast<f16x8*>(&zb[r * 128 + ((fl * 8) ^ ((r & 7) << 3))]) = w;
      }
    }
  }
  __syncthreads();
  if (!act) return;

  // ---------------- GEMM: 16 x 128, K = 128 ----------------
  int lr = lane & 15, kg = lane >> 4;
  f32x4 acc[8];
#pragma unroll
  for (int n = 0; n < 8; ++n) acc[n] = {0.f, 0.f, 0.f, 0.f};

  const __half* Bb = Bf + kg * 128 + lr * 8;
#pragma unroll
  for (int kt = 0; kt < 4; ++kt) {
    f16x8 a = *reinterpret_cast<const f16x8*>(
        &zb[lr * 128 + ((kt * 32 + kg * 8) ^ ((lr & 7) << 3))]);
#pragma unroll
    for (int n = 0; n < 8; ++n) {
      f16x8 b = *reinterpret_cast<const f16x8*>(Bb + n * 2048 + kt * 512);
      acc[n] = __builtin_amdgcn_mfma_f32_16x16x32_f16(a, b, acc[n], 0, 0, 0);
    }
  }

  // epilogue: C(row = kg*4 + q, col = n*16 + lr)
#pragma unroll
  for (int q = 0; q < 4; ++q) {
    int gr = row0 + kg * 4 + q;
    float dv = (EPI == 0) ? dinv[gr] : 0.f;
#pragma unroll
    for (int n = 0; n < 8; ++n) {
      int gc = n * 16 + lr;
      float v = fmaxf(acc[n][q], 0.f);
      if (EPI == 0) {
        Cs[(size_t)gr * HIDC + gc] = __float2half(v * dv);
      } else {
        Cff[fraddr(gr, gc, HIDC)] = __float2half(v);
      }
    }
  }
}

// ---------------- fp16 fragment GEMM for output projection ----------------

__global__ void __launch_bounds__(256) k_fgemm_out(
    const __half* __restrict__ Af, const __half* __restrict__ Bf,
    const float* __restrict__ bias, float* __restrict__ Cf) {
  constexpr int NF = OUTC / 16;
  int wv = threadIdx.x >> 6, lane = threadIdx.x & 63;
  int lr = lane & 15, kg = lane >> 4;
  int w32 = blockIdx.x * 4 + wv;
  if (w32 >= NW32) return;
  int row0 = w32 * 32;

  f32x4 acc[2][NF];
#pragma unroll
  for (int m = 0; m < 2; ++m)
#pragma unroll
    for (int n = 0; n < NF; ++n) acc[m][n] = {0.f, 0.f, 0.f, 0.f};

  const __half* Ab = Af + (size_t)(w32 * 2) * 2048 + kg * 128 + lr * 8;
  const __half* Bb = Bf + kg * 128 + lr * 8;

#pragma unroll
  for (int kt = 0; kt < 4; ++kt) {
    f16x8 a0 = *reinterpret_cast<const f16x8*>(Ab + kt * 512);
    f16x8 a1 = *reinterpret_cast<const f16x8*>(Ab + 2048 + kt * 512);
#pragma unroll
    for (int n = 0; n < NF; ++n) {
      f16x8 b = *reinterpret_cast<const f16x8*>(Bb + n * 2048 + kt * 512);
      acc[0][n] = __builtin_amdgcn_mfma_f32_16x16x32_f16(a0, b, acc[0][n], 0, 0, 0);
      acc[1][n] = __builtin_amdgcn_mfma_f32_16x16x32_f16(a1, b, acc[1][n], 0, 0, 0);
    }
  }

#pragma unroll
  for (int m = 0; m < 2; ++m) {
#pragma unroll
    for (int q = 0; q < 4; ++q) {
      int gr = row0 + m * 16 + kg * 4 + q;
#pragma unroll
      for (int n = 0; n < NF; ++n) {
        int gc = n * 16 + lr;
        Cf[(size_t)gr * OUTC + gc] = acc[m][n][q] + bias[gc];
      }
    }
  }
}

// ---------------- launch ----------------

extern "C" void kernel_launch(void* const* d_in, const int* in_sizes, int n_in,
                              void* d_out, int out_size, void* d_ws, size_t ws_size,
                              hipStream_t stream) {
  const float* x     = (const float*)d_in[0];
  const int*   ei    = (const int*)d_in[1];
  const float* W_in  = (const float*)d_in[2];
  const float* b_in  = (const float*)d_in[3];
  const float* W_cv  = (const float*)d_in[4];
  const float* W_out = (const float*)d_in[5];
  const float* b_out = (const float*)d_in[6];
  float* out = (float*)d_out;

  char* ws = (char*)d_ws;
  size_t off = 0;
  auto alloc = [&](size_t bytes) {
    char* p = ws + off;
    off = (off + bytes + 255) & ~(size_t)255;
    return p;
  };
  int*    deg     = (int*)alloc((size_t)NN * 4);
  int*    row_ptr = (int*)alloc((size_t)NN * 4);
  int*    cursor  = (int*)alloc((size_t)NN * 4);
  int*    bsum    = (int*)alloc(512 * 4);
  float*  dinv    = (float*)alloc((size_t)NN * 4);
  int*    col     = (int*)alloc((size_t)(EE + NN) * 4);
  __half* h016u   = (__half*)alloc((size_t)NN * HIDC * 2);
  __half* h016s   = (__half*)alloc((size_t)NN * HIDC * 2);
  __half* hsA     = (__half*)alloc((size_t)NN * HIDC * 2);
  __half* hsB     = (__half*)alloc((size_t)NN * HIDC * 2);
  __half* hf      = (__half*)alloc((size_t)NN * HIDC * 2);
  __half* wcv16   = (__half*)alloc((size_t)NLAYER * HIDC * HIDC * 2);
  __half* wout16  = (__half*)alloc((size_t)OUTC * HIDC * 2);
  unsigned short* win_h = (unsigned short*)alloc((size_t)HIDC * 512 * 2);
  unsigned short* win_l = (unsigned short*)alloc((size_t)HIDC * 512 * 2);

  const int* srcp = ei;
  const int* dstp = ei + EE;

  hipMemsetAsync(deg, 0, (size_t)NN * 4, stream);
  k_count_deg<<<(EE + 255) / 256, 256, 0, stream>>>(dstp, deg, EE);
  int nb = (NN + 255) / 256;  // 391 <= 512
  k_scan_block_sums<<<nb, 256, 0, stream>>>(deg, bsum, NN);
  k_scan_partials<<<1, 512, 0, stream>>>(bsum, nb);
  k_scan_final<<<nb, 256, 0, stream>>>(deg, bsum, row_ptr, NN);
  k_init_rows<<<(NN + 255) / 256, 256, 0, stream>>>(deg, row_ptr, cursor, col, dinv, NN);

  // weight prep
  k_prep_wfin<<<(HIDC * 512 + 255) / 256, 256, 0, stream>>>(W_in, win_h, win_l);
  for (int l = 0; l < NLAYER; ++l) {
    float beta = logf(0.5f / (float)(l + 1) + 1.0f);
    k_prep_wf16<<<(HIDC * HIDC + 255) / 256, 256, 0, stream>>>(
        W_cv + (size_t)l * HIDC * HIDC, wcv16 + (size_t)l * HIDC * HIDC,
        HIDC, HIDC, 1.0f - beta, beta);
  }
  k_prep_wf16<<<(OUTC * HIDC + 255) / 256, 256, 0, stream>>>(W_out, wout16, HIDC, OUTC,
                                                             0.f, 1.f);

  // FUSED: CSR fill  ∥  h0 = relu(x @ W_in + b_in) -> fp16 unscaled + scaled
  k_fill_gemm<<<FUSE_BLKS, 256, 0, stream>>>(srcp, dstp, cursor, col,
                                             x, win_h, win_l, b_in,
                                             h016u, h016s, dinv);

  int lgrid = (NW16 + 3) / 4;  // 1563
  const __half* hcur = h016s;
  for (int l = 0; l < NLAYER; ++l) {
    const __half* wl = wcv16 + (size_t)l * HIDC * HIDC;
    if (l < NLAYER - 1) {
      __half* tgt = (l & 1) ? hsB : hsA;
      k_layer<0><<<lgrid, 256, 0, stream>>>(hcur, h016u, wl, row_ptr, deg, col, dinv,
                                            tgt, nullptr);
      hcur = tgt;
    } else {
      k_layer<1><<<lgrid, 256, 0, stream>>>(hcur, h016u, wl, row_ptr, deg, col, dinv,
                                            nullptr, hf);
    }
  }
  // out = h @ W_out + b_out
  k_fgemm_out<<<(NW32 + 3) / 4, 256, 0, stream>>>(hf, wout16, b_out, out);
}

// Round 10
// 1022.236 us; speedup vs baseline: 1.3844x; 1.3844x over previous
//
#include <hip/hip_runtime.h>
#include <hip/hip_fp16.h>
#include <cmath>

#define NN 100000
#define EE 1600000
#define INC 500
#define HIDC 128
#define OUTC 64
#define NLAYER 8
#define NW32 3125           // NN / 32 exactly
#define NB16 6250           // NN / 16 exactly
#define FUSE_BLKS 7032      // 9*781 + 3 : bid%9==0 -> gemm (782), else fill (6250)

typedef float f32x4 __attribute__((ext_vector_type(4)));
typedef __bf16 bf16x8 __attribute__((ext_vector_type(8)));
typedef _Float16 f16x8 __attribute__((ext_vector_type(8)));
typedef short s16x4 __attribute__((ext_vector_type(4)));
typedef short s16x8 __attribute__((ext_vector_type(8)));

__device__ __forceinline__ unsigned short f2bf_rn(float f) {
  unsigned u = __float_as_uint(f);
  unsigned r = u + 0x7fffu + ((u >> 16) & 1u);
  return (unsigned short)(r >> 16);
}
__device__ __forceinline__ float bf2f(unsigned short h) {
  return __uint_as_float(((unsigned)h) << 16);
}

// frag layout addr for (row, k), K pitch Kp: [(row/16)][k/8][row%16][k%8]
__device__ __forceinline__ int fraddr(int row, int k, int Kp) {
  return (row >> 4) * (Kp * 16) + (k >> 3) * 128 + (row & 15) * 8 + (k & 7);
}

// ---------------- graph preprocessing ----------------

__global__ void k_count_deg(const int* __restrict__ dst, int* __restrict__ deg, int E) {
  int e = blockIdx.x * blockDim.x + threadIdx.x;
  if (e < E) atomicAdd(&deg[dst[e]], 1);
}

__global__ void k_scan_block_sums(const int* __restrict__ deg, int* __restrict__ bsum, int n) {
  __shared__ int sm[256];
  int i = blockIdx.x * 256 + threadIdx.x;
  int v = (i < n) ? deg[i] + 1 : 0;  // +1 for self-loop
  sm[threadIdx.x] = v;
  __syncthreads();
  for (int s = 128; s > 0; s >>= 1) {
    if (threadIdx.x < s) sm[threadIdx.x] += sm[threadIdx.x + s];
    __syncthreads();
  }
  if (threadIdx.x == 0) bsum[blockIdx.x] = sm[0];
}

__global__ void k_scan_partials(int* __restrict__ bsum, int nb) {
  __shared__ int sm[512];
  int t = threadIdx.x;
  sm[t] = (t < nb) ? bsum[t] : 0;
  __syncthreads();
  for (int s = 1; s < 512; s <<= 1) {
    int v = (t >= s) ? sm[t - s] : 0;
    __syncthreads();
    sm[t] += v;
    __syncthreads();
  }
  if (t < nb) bsum[t] = (t == 0) ? 0 : sm[t - 1];  // exclusive
}

__global__ void k_scan_final(const int* __restrict__ deg, const int* __restrict__ bsum,
                             int* __restrict__ row_ptr, int n) {
  __shared__ int sm[256];
  int i = blockIdx.x * 256 + threadIdx.x;
  int v = (i < n) ? deg[i] + 1 : 0;
  sm[threadIdx.x] = v;
  __syncthreads();
  for (int s = 1; s < 256; s <<= 1) {
    int u = (threadIdx.x >= s) ? sm[threadIdx.x - s] : 0;
    __syncthreads();
    sm[threadIdx.x] += u;
    __syncthreads();
  }
  if (i < n) row_ptr[i] = bsum[blockIdx.x] + sm[threadIdx.x] - v;  // exclusive
}

__global__ void k_init_rows(const int* __restrict__ deg, const int* __restrict__ row_ptr,
                            int* __restrict__ cursor, int* __restrict__ col,
                            float* __restrict__ dinv, int n) {
  int i = blockIdx.x * blockDim.x + threadIdx.x;
  if (i < n) {
    int rp = row_ptr[i];
    col[rp] = i;          // self-loop entry first (deterministic)
    cursor[i] = rp + 1;
    dinv[i] = rsqrtf((float)(deg[i] + 1));
  }
}

// ---- W_in -> FRAGMENT layout hi/lo bf16, Kp=512 ----

__global__ void k_prep_wfin(const float* __restrict__ W, unsigned short* __restrict__ fh,
                            unsigned short* __restrict__ fl) {
  int i = blockIdx.x * 256 + threadIdx.x;
  if (i >= HIDC * 512) return;
  int n = i / 512, k = i % 512;
  float v = (k < INC) ? W[(size_t)k * HIDC + n] : 0.f;
  unsigned short h = f2bf_rn(v);
  unsigned short l = f2bf_rn(v - bf2f(h));
  int a = fraddr(n, k, 512);
  fh[a] = h;
  fl[a] = l;
}

// ---- W -> fp16 fragment layout, optional identity fold: M = idc*I + ws*W ----

__global__ void k_prep_wf16(const float* __restrict__ W, __half* __restrict__ f,
                            int K, int N, float idc, float ws) {
  int i = blockIdx.x * 256 + threadIdx.x;
  if (i >= N * K) return;
  int n = i / K, k = i % K;
  float v = ws * W[(size_t)k * N + n] + ((k == n) ? idc : 0.f);
  f[fraddr(n, k, K)] = __float2half(v);
}

// ---------------- FUSED: CSR edge fill  ∥  input-projection GEMM ----------------

__global__ void __launch_bounds__(256) k_fill_gemm(
    const int* __restrict__ src, const int* __restrict__ dst,
    int* __restrict__ cursor, int* __restrict__ col,
    const float* __restrict__ A, const unsigned short* __restrict__ Bfh,
    const unsigned short* __restrict__ Bfl, const float* __restrict__ bias,
    __half* __restrict__ C16u, __half* __restrict__ C16s,
    const float* __restrict__ dinv) {
  __shared__ __align__(16) unsigned short Ah[128 * 40];
  __shared__ __align__(16) unsigned short Al[128 * 40];
  int bid = blockIdx.x;
  int tid = threadIdx.x;

  if (bid % 9 != 0) {
    // ---------------- fill branch ----------------
    int fidx = bid - (bid / 9 + 1);
    int e = fidx * 256 + tid;
    if (e < EE) {
      int pos = atomicAdd(&cursor[dst[e]], 1);
      col[pos] = src[e];
    }
    return;
  }

  // ---------------- gemm branch ----------------
  int blk = bid / 9;
  int wid = tid >> 6, lane = tid & 63;
  int wr = wid >> 1, wc = wid & 1;
  int lr = lane & 15, kg = lane >> 4;
  int row0 = blk * 128;

  f32x4 acc[4][4];
#pragma unroll
  for (int m = 0; m < 4; ++m)
#pragma unroll
    for (int n = 0; n < 4; ++n) acc[m][n] = {0.f, 0.f, 0.f, 0.f};

  float4 va[4];
  auto issue_loads = [&](int kt) {
#pragma unroll
    for (int p = 0; p < 4; ++p) {
      int idx = tid + p * 256;
      int r = idx >> 3, kq = idx & 7;
      int gr = row0 + r, gk = kt + kq * 4;
      va[p] = make_float4(0.f, 0.f, 0.f, 0.f);
      if (gr < NN && gk < INC) va[p] = *reinterpret_cast<const float4*>(&A[(size_t)gr * INC + gk]);
    }
  };

  issue_loads(0);
  for (int kt = 0; kt < 512; kt += 32) {
    // convert regs -> LDS (hi/lo bf16)
#pragma unroll
    for (int p = 0; p < 4; ++p) {
      int idx = tid + p * 256;
      int r = idx >> 3, kq = idx & 7;
      const float* vp = &va[p].x;
      s16x4 h4, l4;
#pragma unroll
      for (int e = 0; e < 4; ++e) {
        unsigned short h = f2bf_rn(vp[e]);
        h4[e] = (short)h;
        l4[e] = (short)f2bf_rn(vp[e] - bf2f(h));
      }
      *reinterpret_cast<s16x4*>(&Ah[r * 40 + kq * 4]) = h4;
      *reinterpret_cast<s16x4*>(&Al[r * 40 + kq * 4]) = l4;
    }
    __syncthreads();
    if (kt + 32 < 512) issue_loads(kt + 32);  // overlaps MFMA below

    bf16x8 afh[4], afl[4];
#pragma unroll
    for (int m = 0; m < 4; ++m) {
      int r = wr * 64 + m * 16 + lr;
      afh[m] = *reinterpret_cast<const bf16x8*>(&Ah[r * 40 + kg * 8]);
      afl[m] = *reinterpret_cast<const bf16x8*>(&Al[r * 40 + kg * 8]);
    }
#pragma unroll
    for (int n = 0; n < 4; ++n) {
      size_t bb = (size_t)(wc * 4 + n) * 8192 + (size_t)(kt / 8 + kg) * 128 + lr * 8;
      bf16x8 bh = *reinterpret_cast<const bf16x8*>(&Bfh[bb]);
      bf16x8 bl = *reinterpret_cast<const bf16x8*>(&Bfl[bb]);
#pragma unroll
      for (int m = 0; m < 4; ++m) {
        acc[m][n] = __builtin_amdgcn_mfma_f32_16x16x32_bf16(afh[m], bh, acc[m][n], 0, 0, 0);
        acc[m][n] = __builtin_amdgcn_mfma_f32_16x16x32_bf16(afl[m], bh, acc[m][n], 0, 0, 0);
        acc[m][n] = __builtin_amdgcn_mfma_f32_16x16x32_bf16(afh[m], bl, acc[m][n], 0, 0, 0);
      }
    }
    __syncthreads();
  }

  // epilogue: C(row = m*16 + kg*4 + q, col = n*16 + lr)
#pragma unroll
  for (int m = 0; m < 4; ++m) {
#pragma unroll
    for (int n = 0; n < 4; ++n) {
      int gc = wc * 64 + n * 16 + lr;
#pragma unroll
      for (int q = 0; q < 4; ++q) {
        int gr = row0 + wr * 64 + m * 16 + kg * 4 + q;
        if (gr < NN) {
          float v = fmaxf(acc[m][n][q] + bias[gc], 0.f);
          C16u[(size_t)gr * HIDC + gc] = __float2half(v);
          C16s[(size_t)gr * HIDC + gc] = __float2half(v * dinv[gr]);
        }
      }
    }
  }
}

// ---------------- FUSED layer: 16 waves = 16 nodes (1 wave/node) + 16x128 GEMM ----------------
// Gather keeps full TLP (100K waves). z -> LDS (fp16, XOR-swizzled rows).
// After barrier, waves 0..7 each compute one 16x16 output fragment (4 MFMAs).
// EPI 0: relu -> fp16 scaled row-major (feeds next layer's agg)
// EPI 1: relu -> fp16 frag layout (last layer, feeds out GEMM)

template <int EPI>
__global__ void __launch_bounds__(1024) k_layer(
    const __half* __restrict__ hs, const __half* __restrict__ h0u,
    const __half* __restrict__ Bf,
    const int* __restrict__ row_ptr, const int* __restrict__ deg,
    const int* __restrict__ col, const float* __restrict__ dinv,
    __half* __restrict__ Cs, __half* __restrict__ Cff) {
  __shared__ __half zb[16 * 128];   // 4 KB
  int wv = threadIdx.x >> 6, lane = threadIdx.x & 63;
  int g = lane >> 4;    // edge slot within chunk
  int fl = lane & 15;   // feature sub-lane
  int row0 = blockIdx.x * 16;
  int node = row0 + wv;                 // NN == 6250*16 exactly

  // ---- gather: one wave per node (same structure as the proven k_agg) ----
  int start = row_ptr[node];
  int cnt = deg[node] + 1;
  int nch = (cnt + 3) >> 2;

  float acc[8];
#pragma unroll
  for (int j = 0; j < 8; ++j) acc[j] = 0.f;

  auto load_chunk = [&](int ch, s16x8& v, float& m) {
    int e = ch * 4 + g;
    bool valid = e < cnt;
    int c = col[start + (valid ? e : 0)];
    m = valid ? 1.f : 0.f;
    v = *reinterpret_cast<const s16x8*>(&hs[(size_t)c * HIDC + fl * 8]);
  };

  s16x8 curv; float curm;
  load_chunk(0, curv, curm);
  for (int ch = 0; ch < nch; ++ch) {
    s16x8 nv = {}; float nm = 0.f;
    if (ch + 1 < nch) load_chunk(ch + 1, nv, nm);
    const __half2* hp = reinterpret_cast<const __half2*>(&curv);
#pragma unroll
    for (int j = 0; j < 4; ++j) {
      float2 f = __half22float2(hp[j]);
      acc[2 * j]     = fmaf(curm, f.x, acc[2 * j]);
      acc[2 * j + 1] = fmaf(curm, f.y, acc[2 * j + 1]);
    }
    curv = nv; curm = nm;
  }

#pragma unroll
  for (int j = 0; j < 8; ++j) {
    acc[j] += __shfl_xor(acc[j], 16, 64);
    acc[j] += __shfl_xor(acc[j], 32, 64);
  }

  if (g == 0) {
    float dr = dinv[node] * 0.9f;
    s16x8 r0 = *reinterpret_cast<const s16x8*>(&h0u[(size_t)node * HIDC + fl * 8]);
    const __half2* r0p = reinterpret_cast<const __half2*>(&r0);
    f16x8 w;
#pragma unroll
    for (int j = 0; j < 4; ++j) {
      float2 f0 = __half22float2(r0p[j]);
      w[2 * j]     = (_Float16)fmaf(dr, acc[2 * j],     0.1f * f0.x);
      w[2 * j + 1] = (_Float16)fmaf(dr, acc[2 * j + 1], 0.1f * f0.y);
    }
    *reinterpret_cast<f16x8*>(&zb[wv * 128 + ((fl * 8) ^ ((wv & 7) << 3))]) = w;
  }
  __syncthreads();

  // ---- GEMM: 16 x 128, K = 128; wave n (n<8) computes column-frag n ----
  if (wv < 8) {
    int lr = lane & 15, kg = lane >> 4;
    f32x4 c = {0.f, 0.f, 0.f, 0.f};
    const __half* Bb = Bf + wv * 2048 + kg * 128 + lr * 8;
#pragma unroll
    for (int kt = 0; kt < 4; ++kt) {
      f16x8 a = *reinterpret_cast<const f16x8*>(
          &zb[lr * 128 + ((kt * 32 + kg * 8) ^ ((lr & 7) << 3))]);
      f16x8 b = *reinterpret_cast<const f16x8*>(Bb + kt * 512);
      c = __builtin_amdgcn_mfma_f32_16x16x32_f16(a, b, c, 0, 0, 0);
    }
    // epilogue: row = kg*4 + q, col = wv*16 + lr
    int gc = wv * 16 + lr;
#pragma unroll
    for (int q = 0; q < 4; ++q) {
      int gr = row0 + kg * 4 + q;
      float v = fmaxf(c[q], 0.f);
      if (EPI == 0) {
        Cs[(size_t)gr * HIDC + gc] = __float2half(v * dinv[gr]);
      } else {
        Cff[fraddr(gr, gc, HIDC)] = __float2half(v);
      }
    }
  }
}

// ---------------- fp16 fragment GEMM for output projection ----------------

__global__ void __launch_bounds__(256) k_fgemm_out(
    const __half* __restrict__ Af, const __half* __restrict__ Bf,
    const float* __restrict__ bias, float* __restrict__ Cf) {
  constexpr int NF = OUTC / 16;
  int wv = threadIdx.x >> 6, lane = threadIdx.x & 63;
  int lr = lane & 15, kg = lane >> 4;
  int w32 = blockIdx.x * 4 + wv;
  if (w32 >= NW32) return;
  int row0 = w32 * 32;

  f32x4 acc[2][NF];
#pragma unroll
  for (int m = 0; m < 2; ++m)
#pragma unroll
    for (int n = 0; n < NF; ++n) acc[m][n] = {0.f, 0.f, 0.f, 0.f};

  const __half* Ab = Af + (size_t)(w32 * 2) * 2048 + kg * 128 + lr * 8;
  const __half* Bb = Bf + kg * 128 + lr * 8;

#pragma unroll
  for (int kt = 0; kt < 4; ++kt) {
    f16x8 a0 = *reinterpret_cast<const f16x8*>(Ab + kt * 512);
    f16x8 a1 = *reinterpret_cast<const f16x8*>(Ab + 2048 + kt * 512);
#pragma unroll
    for (int n = 0; n < NF; ++n) {
      f16x8 b = *reinterpret_cast<const f16x8*>(Bb + n * 2048 + kt * 512);
      acc[0][n] = __builtin_amdgcn_mfma_f32_16x16x32_f16(a0, b, acc[0][n], 0, 0, 0);
      acc[1][n] = __builtin_amdgcn_mfma_f32_16x16x32_f16(a1, b, acc[1][n], 0, 0, 0);
    }
  }

#pragma unroll
  for (int m = 0; m < 2; ++m) {
#pragma unroll
    for (int q = 0; q < 4; ++q) {
      int gr = row0 + m * 16 + kg * 4 + q;
#pragma unroll
      for (int n = 0; n < NF; ++n) {
        int gc = n * 16 + lr;
        Cf[(size_t)gr * OUTC + gc] = acc[m][n][q] + bias[gc];
      }
    }
  }
}

// ---------------- launch ----------------

extern "C" void kernel_launch(void* const* d_in, const int* in_sizes, int n_in,
                              void* d_out, int out_size, void* d_ws, size_t ws_size,
                              hipStream_t stream) {
  const float* x     = (const float*)d_in[0];
  const int*   ei    = (const int*)d_in[1];
  const float* W_in  = (const float*)d_in[2];
  const float* b_in  = (const float*)d_in[3];
  const float* W_cv  = (const float*)d_in[4];
  const float* W_out = (const float*)d_in[5];
  const float* b_out = (const float*)d_in[6];
  float* out = (float*)d_out;

  char* ws = (char*)d_ws;
  size_t off = 0;
  auto alloc = [&](size_t bytes) {
    char* p = ws + off;
    off = (off + bytes + 255) & ~(size_t)255;
    return p;
  };
  int*    deg     = (int*)alloc((size_t)NN * 4);
  int*    row_ptr = (int*)alloc((size_t)NN * 4);
  int*    cursor  = (int*)alloc((size_t)NN * 4);
  int*    bsum    = (int*)alloc(512 * 4);
  float*  dinv    = (float*)alloc((size_t)NN * 4);
  int*    col     = (int*)alloc((size_t)(EE + NN) * 4);
  __half* h016u   = (__half*)alloc((size_t)NN * HIDC * 2);
  __half* h016s   = (__half*)alloc((size_t)NN * HIDC * 2);
  __half* hsA     = (__half*)alloc((size_t)NN * HIDC * 2);
  __half* hsB     = (__half*)alloc((size_t)NN * HIDC * 2);
  __half* hf      = (__half*)alloc((size_t)NN * HIDC * 2);
  __half* wcv16   = (__half*)alloc((size_t)NLAYER * HIDC * HIDC * 2);
  __half* wout16  = (__half*)alloc((size_t)OUTC * HIDC * 2);
  unsigned short* win_h = (unsigned short*)alloc((size_t)HIDC * 512 * 2);
  unsigned short* win_l = (unsigned short*)alloc((size_t)HIDC * 512 * 2);

  const int* srcp = ei;
  const int* dstp = ei + EE;

  hipMemsetAsync(deg, 0, (size_t)NN * 4, stream);
  k_count_deg<<<(EE + 255) / 256, 256, 0, stream>>>(dstp, deg, EE);
  int nb = (NN + 255) / 256;  // 391 <= 512
  k_scan_block_sums<<<nb, 256, 0, stream>>>(deg, bsum, NN);
  k_scan_partials<<<1, 512, 0, stream>>>(bsum, nb);
  k_scan_final<<<nb, 256, 0, stream>>>(deg, bsum, row_ptr, NN);
  k_init_rows<<<(NN + 255) / 256, 256, 0, stream>>>(deg, row_ptr, cursor, col, dinv, NN);

  // weight prep
  k_prep_wfin<<<(HIDC * 512 + 255) / 256, 256, 0, stream>>>(W_in, win_h, win_l);
  for (int l = 0; l < NLAYER; ++l) {
    float beta = logf(0.5f / (float)(l + 1) + 1.0f);
    k_prep_wf16<<<(HIDC * HIDC + 255) / 256, 256, 0, stream>>>(
        W_cv + (size_t)l * HIDC * HIDC, wcv16 + (size_t)l * HIDC * HIDC,
        HIDC, HIDC, 1.0f - beta, beta);
  }
  k_prep_wf16<<<(OUTC * HIDC + 255) / 256, 256, 0, stream>>>(W_out, wout16, HIDC, OUTC,
                                                             0.f, 1.f);

  // FUSED: CSR fill  ∥  h0 = relu(x @ W_in + b_in) -> fp16 unscaled + scaled
  k_fill_gemm<<<FUSE_BLKS, 256, 0, stream>>>(srcp, dstp, cursor, col,
                                             x, win_h, win_l, b_in,
                                             h016u, h016s, dinv);

  const __half* hcur = h016s;
  for (int l = 0; l < NLAYER; ++l) {
    const __half* wl = wcv16 + (size_t)l * HIDC * HIDC;
    if (l < NLAYER - 1) {
      __half* tgt = (l & 1) ? hsB : hsA;
      k_layer<0><<<NB16, 1024, 0, stream>>>(hcur, h016u, wl, row_ptr, deg, col, dinv,
                                            tgt, nullptr);
      hcur = tgt;
    } else {
      k_layer<1><<<NB16, 1024, 0, stream>>>(hcur, h016u, wl, row_ptr, deg, col, dinv,
                                            nullptr, hf);
    }
  }
  // out = h @ W_out + b_out
  k_fgemm_out<<<(NW32 + 3) / 4, 256, 0, stream>>>(hf, wout16, b_out, out);
}

// Round 11
// 915.473 us; speedup vs baseline: 1.5458x; 1.1166x over previous
//
#include <hip/hip_runtime.h>
#include <hip/hip_fp16.h>
#include <cmath>

#define NN 100000
#define EE 1600000
#define INC 500
#define HIDC 128
#define OUTC 64
#define NLAYER 8
#define NB16 6250           // NN / 16 exactly
#define NPX 12500           // NN / 8 (nodes per XCD bucket)
#define GEMM_BLKS 782       // ceil(NN/128)
#define CNT_BLKS 50000      // 6250 chunks * 8 buckets
#define CG_BLKS (GEMM_BLKS + CNT_BLKS)

typedef float f32x4 __attribute__((ext_vector_type(4)));
typedef __bf16 bf16x8 __attribute__((ext_vector_type(8)));
typedef _Float16 f16x8 __attribute__((ext_vector_type(8)));
typedef short s16x4 __attribute__((ext_vector_type(4)));
typedef short s16x8 __attribute__((ext_vector_type(8)));

__device__ __forceinline__ unsigned short f2bf_rn(float f) {
  unsigned u = __float_as_uint(f);
  unsigned r = u + 0x7fffu + ((u >> 16) & 1u);
  return (unsigned short)(r >> 16);
}
__device__ __forceinline__ float bf2f(unsigned short h) {
  return __uint_as_float(((unsigned)h) << 16);
}

// frag layout addr for (row, k), K pitch Kp: [(row/16)][k/8][row%16][k%8]
__device__ __forceinline__ int fraddr(int row, int k, int Kp) {
  return (row >> 4) * (Kp * 16) + (k >> 3) * 128 + (row & 15) * 8 + (k & 7);
}

// ---------------- graph preprocessing ----------------

__global__ void k_scan_block_sums(const int* __restrict__ deg, int* __restrict__ bsum, int n) {
  __shared__ int sm[256];
  int i = blockIdx.x * 256 + threadIdx.x;
  int v = (i < n) ? deg[i] + 1 : 0;  // +1 for self-loop
  sm[threadIdx.x] = v;
  __syncthreads();
  for (int s = 128; s > 0; s >>= 1) {
    if (threadIdx.x < s) sm[threadIdx.x] += sm[threadIdx.x + s];
    __syncthreads();
  }
  if (threadIdx.x == 0) bsum[blockIdx.x] = sm[0];
}

__global__ void k_scan_partials(int* __restrict__ bsum, int nb) {
  __shared__ int sm[512];
  int t = threadIdx.x;
  sm[t] = (t < nb) ? bsum[t] : 0;
  __syncthreads();
  for (int s = 1; s < 512; s <<= 1) {
    int v = (t >= s) ? sm[t - s] : 0;
    __syncthreads();
    sm[t] += v;
    __syncthreads();
  }
  if (t < nb) bsum[t] = (t == 0) ? 0 : sm[t - 1];  // exclusive
}

__global__ void k_scan_final(const int* __restrict__ deg, const int* __restrict__ bsum,
                             int* __restrict__ row_ptr, int n) {
  __shared__ int sm[256];
  int i = blockIdx.x * 256 + threadIdx.x;
  int v = (i < n) ? deg[i] + 1 : 0;
  sm[threadIdx.x] = v;
  __syncthreads();
  for (int s = 1; s < 256; s <<= 1) {
    int u = (threadIdx.x >= s) ? sm[threadIdx.x - s] : 0;
    __syncthreads();
    sm[threadIdx.x] += u;
    __syncthreads();
  }
  if (i < n) row_ptr[i] = bsum[blockIdx.x] + sm[threadIdx.x] - v;  // exclusive
}

__global__ void k_init_rows(const int* __restrict__ deg, const int* __restrict__ row_ptr,
                            int* __restrict__ cursor, int* __restrict__ col,
                            float* __restrict__ dinv, int n) {
  int i = blockIdx.x * blockDim.x + threadIdx.x;
  if (i < n) {
    int rp = row_ptr[i];
    col[rp] = i;          // self-loop entry first (deterministic)
    cursor[i] = rp + 1;
    dinv[i] = rsqrtf((float)(deg[i] + 1));
  }
}

// h016s = h016u * dinv[row]  (row-major fp16, 16B/lane)
__global__ void __launch_bounds__(256) k_scale(
    const __half* __restrict__ hu, const float* __restrict__ dinv,
    __half* __restrict__ hsc) {
  int i = blockIdx.x * 256 + threadIdx.x;   // one thread per 8 features
  int gr = i >> 4, part = i & 15;
  if (gr >= NN) return;
  float dv = dinv[gr];
  s16x8 v = *reinterpret_cast<const s16x8*>(&hu[(size_t)gr * HIDC + part * 8]);
  const __half2* vp = reinterpret_cast<const __half2*>(&v);
  f16x8 w;
#pragma unroll
  for (int j = 0; j < 4; ++j) {
    float2 f = __half22float2(vp[j]);
    w[2 * j]     = (_Float16)(f.x * dv);
    w[2 * j + 1] = (_Float16)(f.y * dv);
  }
  *reinterpret_cast<f16x8*>(&hsc[(size_t)gr * HIDC + part * 8]) = w;
}

// XCD-bucketed CSR fill
__global__ void __launch_bounds__(256) k_fill_x(
    const int* __restrict__ src, const int* __restrict__ dst,
    int* __restrict__ cursor, int* __restrict__ col) {
  int chunk = blockIdx.x >> 3;
  int xcd = blockIdx.x & 7;
  int e = chunk * 256 + threadIdx.x;   // EE == 6250*256 exactly
  int d = dst[e];
  if (d / NPX == xcd) {
    int pos = atomicAdd(&cursor[d], 1);
    col[pos] = src[e];
  }
}

// ---- W_in -> FRAGMENT layout hi/lo bf16, Kp=512 ----

__global__ void k_prep_wfin(const float* __restrict__ W, unsigned short* __restrict__ fh,
                            unsigned short* __restrict__ fl) {
  int i = blockIdx.x * 256 + threadIdx.x;
  if (i >= HIDC * 512) return;
  int n = i / 512, k = i % 512;
  float v = (k < INC) ? W[(size_t)k * HIDC + n] : 0.f;
  unsigned short h = f2bf_rn(v);
  unsigned short l = f2bf_rn(v - bf2f(h));
  int a = fraddr(n, k, 512);
  fh[a] = h;
  fl[a] = l;
}

// ---- W -> fp16 fragment layout, optional identity fold: M = idc*I + ws*W ----

__global__ void k_prep_wf16(const float* __restrict__ W, __half* __restrict__ f,
                            int K, int N, float idc, float ws) {
  int i = blockIdx.x * 256 + threadIdx.x;
  if (i >= N * K) return;
  int n = i / K, k = i % K;
  float v = ws * W[(size_t)k * N + n] + ((k == n) ? idc : 0.f);
  f[fraddr(n, k, K)] = __float2half(v);
}

// ---------------- FUSED: XCD-bucketed degree count  ∥  input-projection GEMM ----------------

__global__ void __launch_bounds__(256) k_count_gemm(
    const int* __restrict__ dst, int* __restrict__ deg,
    const float* __restrict__ A, const unsigned short* __restrict__ Bfh,
    const unsigned short* __restrict__ Bfl, const float* __restrict__ bias,
    __half* __restrict__ C16u) {
  __shared__ __align__(16) unsigned short Ah[128 * 40];
  __shared__ __align__(16) unsigned short Al[128 * 40];
  int bid = blockIdx.x;
  int tid = threadIdx.x;

  if (bid >= GEMM_BLKS) {
    int o = bid - GEMM_BLKS;
    int chunk = o >> 3;
    int xcd = bid & 7;
    int e = chunk * 256 + tid;   // always < EE
    int d = dst[e];
    if (d / NPX == xcd) atomicAdd(&deg[d], 1);
    return;
  }

  // ---------------- gemm branch ----------------
  int blk = bid;
  int wid = tid >> 6, lane = tid & 63;
  int wr = wid >> 1, wc = wid & 1;
  int lr = lane & 15, kg = lane >> 4;
  int row0 = blk * 128;

  f32x4 acc[4][4];
#pragma unroll
  for (int m = 0; m < 4; ++m)
#pragma unroll
    for (int n = 0; n < 4; ++n) acc[m][n] = {0.f, 0.f, 0.f, 0.f};

  float4 va[4];
  auto issue_loads = [&](int kt) {
#pragma unroll
    for (int p = 0; p < 4; ++p) {
      int idx = tid + p * 256;
      int r = idx >> 3, kq = idx & 7;
      int gr = row0 + r, gk = kt + kq * 4;
      va[p] = make_float4(0.f, 0.f, 0.f, 0.f);
      if (gr < NN && gk < INC) va[p] = *reinterpret_cast<const float4*>(&A[(size_t)gr * INC + gk]);
    }
  };

  issue_loads(0);
  for (int kt = 0; kt < 512; kt += 32) {
#pragma unroll
    for (int p = 0; p < 4; ++p) {
      int idx = tid + p * 256;
      int r = idx >> 3, kq = idx & 7;
      const float* vp = &va[p].x;
      s16x4 h4, l4;
#pragma unroll
      for (int e = 0; e < 4; ++e) {
        unsigned short h = f2bf_rn(vp[e]);
        h4[e] = (short)h;
        l4[e] = (short)f2bf_rn(vp[e] - bf2f(h));
      }
      *reinterpret_cast<s16x4*>(&Ah[r * 40 + kq * 4]) = h4;
      *reinterpret_cast<s16x4*>(&Al[r * 40 + kq * 4]) = l4;
    }
    __syncthreads();
    if (kt + 32 < 512) issue_loads(kt + 32);  // overlaps MFMA below

    bf16x8 afh[4], afl[4];
#pragma unroll
    for (int m = 0; m < 4; ++m) {
      int r = wr * 64 + m * 16 + lr;
      afh[m] = *reinterpret_cast<const bf16x8*>(&Ah[r * 40 + kg * 8]);
      afl[m] = *reinterpret_cast<const bf16x8*>(&Al[r * 40 + kg * 8]);
    }
#pragma unroll
    for (int n = 0; n < 4; ++n) {
      size_t bb = (size_t)(wc * 4 + n) * 8192 + (size_t)(kt / 8 + kg) * 128 + lr * 8;
      bf16x8 bh = *reinterpret_cast<const bf16x8*>(&Bfh[bb]);
      bf16x8 bl = *reinterpret_cast<const bf16x8*>(&Bfl[bb]);
#pragma unroll
      for (int m = 0; m < 4; ++m) {
        acc[m][n] = __builtin_amdgcn_mfma_f32_16x16x32_bf16(afh[m], bh, acc[m][n], 0, 0, 0);
        acc[m][n] = __builtin_amdgcn_mfma_f32_16x16x32_bf16(afl[m], bh, acc[m][n], 0, 0, 0);
        acc[m][n] = __builtin_amdgcn_mfma_f32_16x16x32_bf16(afh[m], bl, acc[m][n], 0, 0, 0);
      }
    }
    __syncthreads();
  }

#pragma unroll
  for (int m = 0; m < 4; ++m) {
#pragma unroll
    for (int n = 0; n < 4; ++n) {
      int gc = wc * 64 + n * 16 + lr;
#pragma unroll
      for (int q = 0; q < 4; ++q) {
        int gr = row0 + wr * 64 + m * 16 + kg * 4 + q;
        if (gr < NN) {
          float v = fmaxf(acc[m][n][q] + bias[gc], 0.f);
          C16u[(size_t)gr * HIDC + gc] = __float2half(v);
        }
      }
    }
  }
}

// ---------------- FUSED layer: 16 waves = 16 nodes + 16x128 GEMM (+ out GEMM on last) ----------------

template <int EPI>
__global__ void __launch_bounds__(1024) k_layer(
    const __half* __restrict__ hs, const __half* __restrict__ h0u,
    const __half* __restrict__ Bf,
    const int* __restrict__ row_ptr, const int* __restrict__ deg,
    const int* __restrict__ col, const float* __restrict__ dinv,
    __half* __restrict__ Cs,
    const __half* __restrict__ Bf2, const float* __restrict__ bias2,
    float* __restrict__ outp) {
  __shared__ __half zb[16 * 128];   // 4 KB
  int wv = threadIdx.x >> 6, lane = threadIdx.x & 63;
  int g = lane >> 4;    // edge slot within chunk
  int fl = lane & 15;   // feature sub-lane
  int row0 = blockIdx.x * 16;
  int node = row0 + wv;                 // NN == 6250*16 exactly

  // ---- gather: one wave per node; 64-edge super-chunks, shfl-distributed cols ----
  int start = row_ptr[node];
  int cnt = deg[node] + 1;

  float acc[8];
#pragma unroll
  for (int j = 0; j < 8; ++j) acc[j] = 0.f;

  for (int base = 0; base < cnt; base += 64) {
    int rem = cnt - base;
    if (rem > 64) rem = 64;
    int myc = col[start + base + (lane < rem ? lane : 0)];  // 64 indices, one load
    int nch = (rem + 3) >> 2;

    auto get = [&](int ch, s16x8& v, float& m) {
      int e = ch * 4 + g;
      int c = __shfl(myc, e & 63, 64);
      m = (e < rem) ? 1.f : 0.f;
      v = *reinterpret_cast<const s16x8*>(&hs[(size_t)c * HIDC + fl * 8]);
    };

    s16x8 curv; float curm;
    get(0, curv, curm);
    for (int ch = 0; ch < nch; ++ch) {
      s16x8 nv = {}; float nm = 0.f;
      if (ch + 1 < nch) get(ch + 1, nv, nm);
      const __half2* hp = reinterpret_cast<const __half2*>(&curv);
#pragma unroll
      for (int j = 0; j < 4; ++j) {
        float2 f = __half22float2(hp[j]);
        acc[2 * j]     = fmaf(curm, f.x, acc[2 * j]);
        acc[2 * j + 1] = fmaf(curm, f.y, acc[2 * j + 1]);
      }
      curv = nv; curm = nm;
    }
  }

#pragma unroll
  for (int j = 0; j < 8; ++j) {
    acc[j] += __shfl_xor(acc[j], 16, 64);
    acc[j] += __shfl_xor(acc[j], 32, 64);
  }

  if (g == 0) {
    float dr = dinv[node] * 0.9f;
    s16x8 r0 = *reinterpret_cast<const s16x8*>(&h0u[(size_t)node * HIDC + fl * 8]);
    const __half2* r0p = reinterpret_cast<const __half2*>(&r0);
    f16x8 w;
#pragma unroll
    for (int j = 0; j < 4; ++j) {
      float2 f0 = __half22float2(r0p[j]);
      w[2 * j]     = (_Float16)fmaf(dr, acc[2 * j],     0.1f * f0.x);
      w[2 * j + 1] = (_Float16)fmaf(dr, acc[2 * j + 1], 0.1f * f0.y);
    }
    *reinterpret_cast<f16x8*>(&zb[wv * 128 + ((fl * 8) ^ ((wv & 7) << 3))]) = w;
  }
  __syncthreads();

  // ---- GEMM1: 16 x 128, K = 128; wave n (n<8) computes column-frag n ----
  int lr = lane & 15, kg = lane >> 4;
  f32x4 c = {0.f, 0.f, 0.f, 0.f};
  if (wv < 8) {
    const __half* Bb = Bf + wv * 2048 + kg * 128 + lr * 8;
#pragma unroll
    for (int kt = 0; kt < 4; ++kt) {
      f16x8 a = *reinterpret_cast<const f16x8*>(
          &zb[lr * 128 + ((kt * 32 + kg * 8) ^ ((lr & 7) << 3))]);
      f16x8 b = *reinterpret_cast<const f16x8*>(Bb + kt * 512);
      c = __builtin_amdgcn_mfma_f32_16x16x32_f16(a, b, c, 0, 0, 0);
    }
  }

  if (EPI == 0) {
    if (wv < 8) {
      int gc = wv * 16 + lr;
#pragma unroll
      for (int q = 0; q < 4; ++q) {
        int gr = row0 + kg * 4 + q;
        float v = fmaxf(c[q], 0.f);
        Cs[(size_t)gr * HIDC + gc] = __float2half(v * dinv[gr]);
      }
    }
  } else {
    // ---- last layer: h -> LDS A-frags, then out = h @ W_out + b_out ----
    __syncthreads();   // all GEMM1 zb reads complete
    if (wv < 8) {
      int gc = wv * 16 + lr;   // k index of h
#pragma unroll
      for (int q = 0; q < 4; ++q) {
        int r = kg * 4 + q;
        zb[(gc >> 3) * 128 + r * 8 + (gc & 7)] = __float2half(fmaxf(c[q], 0.f));
      }
    }
    __syncthreads();
    if (wv < 4) {
      f32x4 o = {0.f, 0.f, 0.f, 0.f};
      const __half* Bb2 = Bf2 + wv * 2048 + kg * 128 + lr * 8;
#pragma unroll
      for (int kt = 0; kt < 4; ++kt) {
        f16x8 a = *reinterpret_cast<const f16x8*>(&zb[(kt * 4 + kg) * 128 + lr * 8]);
        f16x8 b = *reinterpret_cast<const f16x8*>(Bb2 + kt * 512);
        o = __builtin_amdgcn_mfma_f32_16x16x32_f16(a, b, o, 0, 0, 0);
      }
      int gc = wv * 16 + lr;
      float bv = bias2[gc];
#pragma unroll
      for (int q = 0; q < 4; ++q) {
        int gr = row0 + kg * 4 + q;
        outp[(size_t)gr * OUTC + gc] = o[q] + bv;
      }
    }
  }
}

// ---------------- launch ----------------

extern "C" void kernel_launch(void* const* d_in, const int* in_sizes, int n_in,
                              void* d_out, int out_size, void* d_ws, size_t ws_size,
                              hipStream_t stream) {
  const float* x     = (const float*)d_in[0];
  const int*   ei    = (const int*)d_in[1];
  const float* W_in  = (const float*)d_in[2];
  const float* b_in  = (const float*)d_in[3];
  const float* W_cv  = (const float*)d_in[4];
  const float* W_out = (const float*)d_in[5];
  const float* b_out = (const float*)d_in[6];
  float* out = (float*)d_out;

  char* ws = (char*)d_ws;
  size_t off = 0;
  auto alloc = [&](size_t bytes) {
    char* p = ws + off;
    off = (off + bytes + 255) & ~(size_t)255;
    return p;
  };
  int*    deg     = (int*)alloc((size_t)NN * 4);
  int*    row_ptr = (int*)alloc((size_t)NN * 4);
  int*    cursor  = (int*)alloc((size_t)NN * 4);
  int*    bsum    = (int*)alloc(512 * 4);
  float*  dinv    = (float*)alloc((size_t)NN * 4);
  int*    col     = (int*)alloc((size_t)(EE + NN) * 4);
  __half* h016u   = (__half*)alloc((size_t)NN * HIDC * 2);
  __half* h016s   = (__half*)alloc((size_t)NN * HIDC * 2);
  __half* hsA     = (__half*)alloc((size_t)NN * HIDC * 2);
  __half* hsB     = (__half*)alloc((size_t)NN * HIDC * 2);
  __half* wcv16   = (__half*)alloc((size_t)NLAYER * HIDC * HIDC * 2);
  __half* wout16  = (__half*)alloc((size_t)OUTC * HIDC * 2);
  unsigned short* win_h = (unsigned short*)alloc((size_t)HIDC * 512 * 2);
  unsigned short* win_l = (unsigned short*)alloc((size_t)HIDC * 512 * 2);

  const int* srcp = ei;
  const int* dstp = ei + EE;

  hipMemsetAsync(deg, 0, (size_t)NN * 4, stream);

  // weight prep (k_count_gemm needs win_h/win_l)
  k_prep_wfin<<<(HIDC * 512 + 255) / 256, 256, 0, stream>>>(W_in, win_h, win_l);
  for (int l = 0; l < NLAYER; ++l) {
    float beta = logf(0.5f / (float)(l + 1) + 1.0f);
    k_prep_wf16<<<(HIDC * HIDC + 255) / 256, 256, 0, stream>>>(
        W_cv + (size_t)l * HIDC * HIDC, wcv16 + (size_t)l * HIDC * HIDC,
        HIDC, HIDC, 1.0f - beta, beta);
  }
  k_prep_wf16<<<(OUTC * HIDC + 255) / 256, 256, 0, stream>>>(W_out, wout16, HIDC, OUTC,
                                                             0.f, 1.f);

  // FUSED: XCD-bucketed degree count  ∥  h0u = relu(x @ W_in + b_in)
  k_count_gemm<<<CG_BLKS, 256, 0, stream>>>(dstp, deg, x, win_h, win_l, b_in, h016u);

  int nb = (NN + 255) / 256;  // 391 <= 512
  k_scan_block_sums<<<nb, 256, 0, stream>>>(deg, bsum, NN);
  k_scan_partials<<<1, 512, 0, stream>>>(bsum, nb);
  k_scan_final<<<nb, 256, 0, stream>>>(deg, bsum, row_ptr, NN);
  k_init_rows<<<(NN + 255) / 256, 256, 0, stream>>>(deg, row_ptr, cursor, col, dinv, NN);

  // h016s = h016u * dinv (needs dinv from k_init_rows)
  k_scale<<<(NN * 16 + 255) / 256, 256, 0, stream>>>(h016u, dinv, h016s);

  // XCD-bucketed CSR fill
  k_fill_x<<<CNT_BLKS, 256, 0, stream>>>(srcp, dstp, cursor, col);

  const __half* hcur = h016s;
  for (int l = 0; l < NLAYER; ++l) {
    const __half* wl = wcv16 + (size_t)l * HIDC * HIDC;
    if (l < NLAYER - 1) {
      __half* tgt = (l & 1) ? hsB : hsA;
      k_layer<0><<<NB16, 1024, 0, stream>>>(hcur, h016u, wl, row_ptr, deg, col, dinv,
                                            tgt, nullptr, nullptr, nullptr);
      hcur = tgt;
    } else {
      k_layer<1><<<NB16, 1024, 0, stream>>>(hcur, h016u, wl, row_ptr, deg, col, dinv,
                                            nullptr, wout16, b_out, out);
    }
  }
}